// Round 13
// baseline (158.158 us; speedup 1.0000x reference)
//
#include <hip/hip_runtime.h>
#include <hip/hip_bf16.h>
#include <math.h>

#define NB 64
#define LD 512
#define LP 1024
#define DD 128
#define KK 64

using half8 = __attribute__((ext_vector_type(8))) _Float16;
using half4 = __attribute__((ext_vector_type(4))) _Float16;
using f32x4 = __attribute__((ext_vector_type(4))) float;

// fast tanh: 1 - 2*rcp(e^{2x}+1) via v_rcp_f32 (no IEEE div sequence).
__device__ __forceinline__ float ftanh(float x) {
    float e = __expf(2.0f * x);
    return 1.0f - 2.0f * __builtin_amdgcn_rcpf(e + 1.0f);
}

// ---------------- conversion kernels ----------------
__global__ void k_conv(const float* __restrict__ in, _Float16* __restrict__ out, int n) {
    int i = (blockIdx.x * blockDim.x + threadIdx.x) * 4;
    int stride = gridDim.x * blockDim.x * 4;
    for (; i < n; i += stride) {
        float4 v = *reinterpret_cast<const float4*>(in + i);
        half4 h;
        h.x = (_Float16)v.x; h.y = (_Float16)v.y; h.z = (_Float16)v.z; h.w = (_Float16)v.w;
        *reinterpret_cast<half4*>(out + i) = h;
    }
}

__global__ void k_wbt(const float* __restrict__ Wb, _Float16* __restrict__ WbT) {
    int t = blockIdx.x * 256 + threadIdx.x;
    int d = t >> 7, e = t & 127;
    WbT[t] = (_Float16)Wb[e * 128 + d];
}

__global__ void k_sentinel(float* out) {
    if (threadIdx.x == 0 && blockIdx.x == 0) out[0] = 1000.0f;
}

// ---------------- plain batched NT GEMM, fp16 in/out (tb, Wxd, Wpt) ----------------
__global__ __launch_bounds__(256)
void k_gemm(const _Float16* __restrict__ A, long sA,
            const _Float16* __restrict__ Bm, long sB,
            _Float16* __restrict__ Out, long sOut,
            int N, int Kd, int tilesM, int tilesN)
{
    __shared__ alignas(16) _Float16 smem[64 * 72 + 128 * 72];
    _Float16* As = smem;
    _Float16* Bs = smem + 64 * 72;

    int bid = blockIdx.x;
    int tpb = tilesM * tilesN;
    int b = bid / tpb;
    int t = bid % tpb;
    int m0 = (t / tilesN) * 64;
    int n0 = (t % tilesN) * 128;

    const _Float16* Ab = A + (long)b * sA;
    const _Float16* Bb = Bm + (long)b * sB;

    int tid = threadIdx.x;
    int lane = tid & 63;
    int wid = tid >> 6;
    int wm = wid & 1, wn = wid >> 1;

    f32x4 acc[2][4];
#pragma unroll
    for (int i = 0; i < 2; i++)
#pragma unroll
        for (int j = 0; j < 4; j++) acc[i][j] = (f32x4)(0.0f);

    for (int k0 = 0; k0 < Kd; k0 += 64) {
#pragma unroll
        for (int i = 0; i < 2; i++) {
            int c = tid + i * 256;
            int row = c >> 3, col = c & 7;
            int4 v = *reinterpret_cast<const int4*>(Ab + (long)(m0 + row) * Kd + k0 + col * 8);
            *reinterpret_cast<int4*>(&As[row * 72 + col * 8]) = v;
        }
#pragma unroll
        for (int i = 0; i < 4; i++) {
            int c = tid + i * 256;
            int row = c >> 3, col = c & 7;
            int4 v = *reinterpret_cast<const int4*>(Bb + (long)(n0 + row) * Kd + k0 + col * 8);
            *reinterpret_cast<int4*>(&Bs[row * 72 + col * 8]) = v;
        }
        __syncthreads();
#pragma unroll
        for (int kk = 0; kk < 64; kk += 32) {
            int klane = kk + 8 * (lane >> 4);
            half8 af[2], bfr[4];
#pragma unroll
            for (int fm = 0; fm < 2; fm++)
                af[fm] = *reinterpret_cast<const half8*>(&As[(wm * 32 + fm * 16 + (lane & 15)) * 72 + klane]);
#pragma unroll
            for (int fn = 0; fn < 4; fn++)
                bfr[fn] = *reinterpret_cast<const half8*>(&Bs[(wn * 64 + fn * 16 + (lane & 15)) * 72 + klane]);
#pragma unroll
            for (int fm = 0; fm < 2; fm++)
#pragma unroll
                for (int fn = 0; fn < 4; fn++)
                    acc[fm][fn] = __builtin_amdgcn_mfma_f32_16x16x32_f16(af[fm], bfr[fn], acc[fm][fn], 0, 0, 0);
        }
        __syncthreads();
    }

    long ob = (long)b * sOut;
#pragma unroll
    for (int fm = 0; fm < 2; fm++)
#pragma unroll
        for (int fn = 0; fn < 4; fn++)
#pragma unroll
            for (int r = 0; r < 4; r++) {
                int row = m0 + wm * 32 + fm * 16 + (lane >> 4) * 4 + r;
                int col = n0 + wn * 64 + fn * 16 + (lane & 15);
                Out[ob + (long)row * N + col] = (_Float16)acc[fm][fn][r];
            }
}

// ---------------- fused C + H + score kernel (both sides, XCD-swizzled) ----------------
// side C (P < 512):  sc_c[b,n0+j] = sum_k whx[k]*tanh(Wxd[k,n0+j] + sum_p Wpt[k,p]*C[p,n0+j])
// side P (P >= 512): sc_p[b,n0+j] = sum_k whp[k]*tanh(Wpt[k,n0+j] + sum_l Wxd[k,l]*C[n0+j,l])
// XCD swizzle (T1): all tile-blocks of a batch share one XCD -> S/W strips L2-resident.
// GEMM operand fragments (af, bf, aw) load DIRECTLY from global/L2 into VGPRs;
// only the Cts transpose (GEMM1 D-layout -> GEMM2 B-layout) goes through LDS.
__global__ __launch_bounds__(256)
void k_score_fused(const _Float16* __restrict__ drug_h, const _Float16* __restrict__ tb_h,
                   const _Float16* __restrict__ Wxd_h, const _Float16* __restrict__ Wpt_h,
                   const float* __restrict__ whx, const float* __restrict__ whp,
                   float* __restrict__ sc_c, float* __restrict__ sc_p)
{
    __shared__ alignas(16) _Float16 Cts[64 * 72];   // C tile [64res][64strm+8]
    __shared__ float sred[8 * 64];
    __shared__ float wsh[64];

    int P = blockIdx.x;
    int tid = threadIdx.x;
    int lane = tid & 63;
    int wid = tid >> 6;
    int wm = wid & 1, wn = wid >> 1;

    int b, n0, nsteps, Ntot, sW;
    const _Float16 *R, *S, *W, *Add;
    const float* wv;
    float* out;
    if (P < 512) {
        int x = P & 7, j = P >> 3;            // x: XCD chunk; j in [0,64)
        b = x * 8 + (j >> 3);
        n0 = (j & 7) * 64;
        R = drug_h + (long)b * (LD * DD);
        S = tb_h   + (long)b * (LP * DD);
        W = Wpt_h  + (long)b * (KK * LP);  sW = LP;
        Add = Wxd_h + (long)b * (KK * LD); Ntot = LD;
        nsteps = LP / 64; wv = whx; out = sc_c + (long)b * LD;
    } else {
        int Q = P - 512;
        int x = Q & 7, j = Q >> 3;            // j in [0,128)
        b = x * 8 + (j >> 4);
        n0 = (j & 15) * 64;
        R = tb_h   + (long)b * (LP * DD);
        S = drug_h + (long)b * (LD * DD);
        W = Wxd_h  + (long)b * (KK * LD);  sW = LD;
        Add = Wpt_h + (long)b * (KK * LP); Ntot = LP;
        nsteps = LD / 64; wv = whp; out = sc_p + (long)b * LP;
    }

    // resident A-fragments in registers (rows never change across steps)
    half8 af[2][4];
#pragma unroll
    for (int fm = 0; fm < 2; fm++)
#pragma unroll
        for (int kk = 0; kk < 4; kk++) {
            int row = n0 + wm * 32 + fm * 16 + (lane & 15);
            int col = kk * 32 + 8 * (lane >> 4);
            af[fm][kk] = *reinterpret_cast<const half8*>(R + (long)row * DD + col);
        }
    if (tid < 64) wsh[tid] = wv[tid];

    f32x4 acc2[2][2];
#pragma unroll
    for (int i = 0; i < 2; i++)
#pragma unroll
        for (int j = 0; j < 2; j++) acc2[i][j] = (f32x4)(0.0f);

    for (int s = 0; s < nsteps; s++) {
        // GEMM1: a1[res, strm] = sum_d af[res,d]*S[strm,d]  (bf direct from L2)
        f32x4 a1[2][2];
#pragma unroll
        for (int i = 0; i < 2; i++)
#pragma unroll
            for (int j = 0; j < 2; j++) a1[i][j] = (f32x4)(0.0f);
        const _Float16* Srow = S + (long)(s * 64) * DD;
#pragma unroll
        for (int kk = 0; kk < 4; kk++) {
            int klane = kk * 32 + 8 * (lane >> 4);
            half8 bf[2];
#pragma unroll
            for (int fn = 0; fn < 2; fn++)
                bf[fn] = *reinterpret_cast<const half8*>(Srow + (long)(wn * 32 + fn * 16 + (lane & 15)) * DD + klane);
#pragma unroll
            for (int fm = 0; fm < 2; fm++)
#pragma unroll
                for (int fn = 0; fn < 2; fn++)
                    a1[fm][fn] = __builtin_amdgcn_mfma_f32_16x16x32_f16(af[fm][kk], bf[fn], a1[fm][fn], 0, 0, 0);
        }
        __syncthreads();                  // (C) prev GEMM2 reads done; Cts free
        // tanh -> Cts [res][strm]
#pragma unroll
        for (int fm = 0; fm < 2; fm++)
#pragma unroll
            for (int fn = 0; fn < 2; fn++)
#pragma unroll
                for (int r = 0; r < 4; r++) {
                    int res  = wm * 32 + fm * 16 + (lane >> 4) * 4 + r;
                    int strm = wn * 32 + fn * 16 + (lane & 15);
                    Cts[res * 72 + strm] = (_Float16)ftanh(a1[fm][fn][r]);
                }
        __syncthreads();                  // (B) Cts ready

        // GEMM2: acc2[k, res] += sum_strm W[k,strm]*Cts[res,strm]  (aw direct from L2)
#pragma unroll
        for (int kk = 0; kk < 2; kk++) {
            int klane = kk * 32 + 8 * (lane >> 4);
            half8 aw[2], bf2[2];
#pragma unroll
            for (int fm = 0; fm < 2; fm++)
                aw[fm] = *reinterpret_cast<const half8*>(W + (long)(wm * 32 + fm * 16 + (lane & 15)) * sW + s * 64 + klane);
#pragma unroll
            for (int fn = 0; fn < 2; fn++)
                bf2[fn] = *reinterpret_cast<const half8*>(&Cts[(wn * 32 + fn * 16 + (lane & 15)) * 72 + klane]);
#pragma unroll
            for (int fm = 0; fm < 2; fm++)
#pragma unroll
                for (int fn = 0; fn < 2; fn++)
                    acc2[fm][fn] = __builtin_amdgcn_mfma_f32_16x16x32_f16(aw[fm], bf2[fn], acc2[fm][fn], 0, 0, 0);
        }
    }

    // epilogue: + Add, tanh, dot w, block reduce over k
    float ps[2] = {0.f, 0.f};
#pragma unroll
    for (int fm = 0; fm < 2; fm++)
#pragma unroll
        for (int fn = 0; fn < 2; fn++)
#pragma unroll
            for (int r = 0; r < 4; r++) {
                int k   = wm * 32 + fm * 16 + (lane >> 4) * 4 + r;
                int col = wn * 32 + fn * 16 + (lane & 15);
                float v = ftanh(acc2[fm][fn][r] + (float)Add[(long)k * Ntot + n0 + col]);
                ps[fn] += wsh[k] * v;
            }
#pragma unroll
    for (int fn = 0; fn < 2; fn++)
        sred[(wm * 4 + (lane >> 4)) * 64 + wn * 32 + fn * 16 + (lane & 15)] = ps[fn];
    __syncthreads();
    if (tid < 64) {
        float sacc = 0.f;
#pragma unroll
        for (int j = 0; j < 8; j++) sacc += sred[j * 64 + tid];
        out[n0 + tid] = sacc;
    }
}

// ---------------- softmax over scores ----------------
__device__ __forceinline__ float wred_max(float v) {
#pragma unroll
    for (int off = 32; off > 0; off >>= 1) v = fmaxf(v, __shfl_xor(v, off, 64));
    return v;
}
__device__ __forceinline__ float wred_sum(float v) {
#pragma unroll
    for (int off = 32; off > 0; off >>= 1) v += __shfl_xor(v, off, 64);
    return v;
}

__global__ __launch_bounds__(1024)
void k_soft(const float* __restrict__ scc, const float* __restrict__ scp,
            float* __restrict__ ac, float* __restrict__ ap)
{
    __shared__ float r16[16];
    int b = blockIdx.x, tid = threadIdx.x;
    int lane = tid & 63, wid = tid >> 6;

    float s = (tid < 512) ? scc[b * 512 + tid] : -3.4e38f;
    float m = wred_max(s);
    if (lane == 0) r16[wid] = m;
    __syncthreads();
    m = r16[0];
#pragma unroll
    for (int i = 1; i < 16; i++) m = fmaxf(m, r16[i]);
    float e = (tid < 512) ? __expf(s - m) : 0.f;
    __syncthreads();
    float t = wred_sum(e);
    if (lane == 0) r16[wid] = t;
    __syncthreads();
    float sum = 0.f;
#pragma unroll
    for (int i = 0; i < 16; i++) sum += r16[i];
    if (tid < 512) ac[b * 512 + tid] = e * __builtin_amdgcn_rcpf(sum);
    __syncthreads();

    float s2 = scp[b * 1024 + tid];
    float m2 = wred_max(s2);
    if (lane == 0) r16[wid] = m2;
    __syncthreads();
    m2 = r16[0];
#pragma unroll
    for (int i = 1; i < 16; i++) m2 = fmaxf(m2, r16[i]);
    float e2 = __expf(s2 - m2);
    __syncthreads();
    float t2 = wred_sum(e2);
    if (lane == 0) r16[wid] = t2;
    __syncthreads();
    float sum2 = 0.f;
#pragma unroll
    for (int i = 0; i < 16; i++) sum2 += r16[i];
    ap[b * 1024 + tid] = e2 * __builtin_amdgcn_rcpf(sum2);
}

// ---------------- weighted sums: out[b,d] = sum_l a[l] * X[b,l,d] ----------------
__global__ __launch_bounds__(512)
void k_wsum(const _Float16* __restrict__ drug_h, const _Float16* __restrict__ targ_h,
            const float* __restrict__ ac, const float* __restrict__ ap,
            float* __restrict__ out)
{
    __shared__ float ash[1024];
    __shared__ float red[32 * 128];
    int b = blockIdx.x, side = blockIdx.y;
    int L = side ? LP : LD;
    const _Float16* X = side ? targ_h : drug_h;
    const float* a = side ? ap : ac;
    float* ob = out + side * 8192 + b * 128;
    int tid = threadIdx.x;

    for (int i = tid; i < L; i += 512) ash[i] = a[(long)b * L + i];
    __syncthreads();

    int col8 = tid & 15, rg = tid >> 4;
    float accv[8];
#pragma unroll
    for (int j = 0; j < 8; j++) accv[j] = 0.f;
    const _Float16* Xb = X + (long)b * L * 128;
    for (int l = rg; l < L; l += 32) {
        half8 v = *reinterpret_cast<const half8*>(&Xb[l * 128 + col8 * 8]);
        float av = ash[l];
#pragma unroll
        for (int j = 0; j < 8; j++) accv[j] += av * (float)v[j];
    }
#pragma unroll
    for (int j = 0; j < 8; j++) red[rg * 128 + col8 * 8 + j] = accv[j];
    __syncthreads();
    if (tid < 128) {
        float s = 0.f;
#pragma unroll
        for (int g = 0; g < 32; g++) s += red[g * 128 + tid];
        ob[tid] = s;
    }
}

// ---------------- launch ----------------
extern "C" void kernel_launch(void* const* d_in, const int* in_sizes, int n_in,
                              void* d_out, int out_size, void* d_ws, size_t ws_size,
                              hipStream_t stream) {
    (void)in_sizes; (void)n_in; (void)out_size;
    const float* drug   = (const float*)d_in[0];
    const float* target = (const float*)d_in[1];
    const float* Wb     = (const float*)d_in[2];
    const float* Wx     = (const float*)d_in[3];
    const float* Wp     = (const float*)d_in[4];
    const float* whx    = (const float*)d_in[5];
    const float* whp    = (const float*)d_in[6];

    char* w = (char*)d_ws;
    size_t off = 0;
    auto takeb = [&](size_t bytes) {
        void* p = (void*)(w + off);
        off += (bytes + 255) & ~(size_t)255;
        return p;
    };
    _Float16* drug_h = (_Float16*)takeb((size_t)NB * LD * DD * 2);
    _Float16* targ_h = (_Float16*)takeb((size_t)NB * LP * DD * 2);
    _Float16* WbT_h  = (_Float16*)takeb(128 * 128 * 2);
    _Float16* Wx_h   = (_Float16*)takeb(64 * 128 * 2);
    _Float16* Wp_h   = (_Float16*)takeb(64 * 128 * 2);
    _Float16* tb_h   = (_Float16*)takeb((size_t)NB * LP * DD * 2);
    _Float16* Wxd_h  = (_Float16*)takeb((size_t)NB * KK * LD * 2);
    _Float16* Wpt_h  = (_Float16*)takeb((size_t)NB * KK * LP * 2);
    float*    sc_c   = (float*)takeb((size_t)NB * LD * 4);
    float*    sc_p   = (float*)takeb((size_t)NB * LP * 4);
    float*    a_c    = (float*)takeb((size_t)NB * LD * 4);
    float*    a_p    = (float*)takeb((size_t)NB * LP * 4);

    if (off > ws_size) {                 // workspace shortfall -> sentinel (absmax ~1000)
        k_sentinel<<<1, 64, 0, stream>>>((float*)d_out);
        return;
    }

    k_conv<<<1024, 256, 0, stream>>>(drug,   drug_h, NB * LD * DD);
    k_conv<<<1024, 256, 0, stream>>>(target, targ_h, NB * LP * DD);
    k_conv<<<16, 256, 0, stream>>>(Wx, Wx_h, 64 * 128);
    k_conv<<<16, 256, 0, stream>>>(Wp, Wp_h, 64 * 128);
    k_wbt<<<64, 256, 0, stream>>>(Wb, WbT_h);

    // tb[p,d] = sum_e target[p,e] * WbT[d,e]            M=LP  N=128 Kd=128
    k_gemm<<<dim3(NB * (LP / 64)), 256, 0, stream>>>(
        targ_h, (long)LP * DD, WbT_h, 0, tb_h, (long)LP * DD, 128, 128, LP / 64, 1);
    // Wxd[k,l] = sum_d Wx[k,d] * drug[l,d]              M=64  N=LD  Kd=128
    k_gemm<<<dim3(NB * (LD / 128)), 256, 0, stream>>>(
        Wx_h, 0, drug_h, (long)LD * DD, Wxd_h, (long)KK * LD, LD, 128, 1, LD / 128);
    // Wpt[k,p] = sum_e Wp[k,e] * target[p,e]            M=64  N=LP  Kd=128
    k_gemm<<<dim3(NB * (LP / 128)), 256, 0, stream>>>(
        Wp_h, 0, targ_h, (long)LP * DD, Wpt_h, (long)KK * LP, LP, 128, 1, LP / 128);

    // fused: C recomputed per side in-LDS; scores out directly
    k_score_fused<<<dim3(512 + 1024), 256, 0, stream>>>(
        drug_h, tb_h, Wxd_h, Wpt_h, whx, whp, sc_c, sc_p);

    k_soft<<<NB, 1024, 0, stream>>>(sc_c, sc_p, a_c, a_p);
    k_wsum<<<dim3(NB, 2), 512, 0, stream>>>(drug_h, targ_h, a_c, a_p, (float*)d_out);
}

// Round 15
// 102.533 us; speedup vs baseline: 1.5425x; 1.5425x over previous
//
#include <hip/hip_runtime.h>
#include <hip/hip_bf16.h>
#include <math.h>

#define NB 64
#define LD 512
#define LP 1024
#define DD 128
#define KK 64

using half8 = __attribute__((ext_vector_type(8))) _Float16;
using half4 = __attribute__((ext_vector_type(4))) _Float16;
using f32x4 = __attribute__((ext_vector_type(4))) float;

// fast tanh: 1 - 2*rcp(e^{2x}+1) via v_rcp_f32 (no IEEE div sequence).
__device__ __forceinline__ float ftanh(float x) {
    float e = __expf(2.0f * x);
    return 1.0f - 2.0f * __builtin_amdgcn_rcpf(e + 1.0f);
}

// ---------------- conversion kernels ----------------
__global__ void k_conv(const float* __restrict__ in, _Float16* __restrict__ out, int n) {
    int i = (blockIdx.x * blockDim.x + threadIdx.x) * 4;
    int stride = gridDim.x * blockDim.x * 4;
    for (; i < n; i += stride) {
        float4 v = *reinterpret_cast<const float4*>(in + i);
        half4 h;
        h.x = (_Float16)v.x; h.y = (_Float16)v.y; h.z = (_Float16)v.z; h.w = (_Float16)v.w;
        *reinterpret_cast<half4*>(out + i) = h;
    }
}

// merged small preps: blocks 0-63 WbT transpose, 64-71 Wx conv, 72-79 Wp conv
__global__ void k_prep(const float* __restrict__ Wb, _Float16* __restrict__ WbT,
                       const float* __restrict__ Wx, _Float16* __restrict__ Wx_h,
                       const float* __restrict__ Wp, _Float16* __restrict__ Wp_h)
{
    int bid = blockIdx.x, tid = threadIdx.x;
    if (bid < 64) {
        int t = bid * 256 + tid;
        int d = t >> 7, e = t & 127;
        WbT[t] = (_Float16)Wb[e * 128 + d];
    } else {
        const float* src = (bid < 72) ? Wx : Wp;
        _Float16* dst = (bid < 72) ? Wx_h : Wp_h;
        int i = ((bid & 7) * 256 + tid) * 4;
        float4 v = *reinterpret_cast<const float4*>(src + i);
        half4 h;
        h.x = (_Float16)v.x; h.y = (_Float16)v.y; h.z = (_Float16)v.z; h.w = (_Float16)v.w;
        *reinterpret_cast<half4*>(dst + i) = h;
    }
}

__global__ void k_sentinel(float* out) {
    if (threadIdx.x == 0 && blockIdx.x == 0) out[0] = 1000.0f;
}

// ---------------- merged NT GEMM dispatch: Wxd + Wpt + tb in one grid ----------------
// ranges: [0,256) Wxd ; [256,768) Wpt ; [768,1792) tb
__global__ __launch_bounds__(256)
void k_gemm3(const _Float16* __restrict__ drug_h, const _Float16* __restrict__ targ_h,
             const _Float16* __restrict__ WbT_h, const _Float16* __restrict__ Wx_h,
             const _Float16* __restrict__ Wp_h,
             _Float16* __restrict__ tb_h, _Float16* __restrict__ Wxd_h,
             _Float16* __restrict__ Wpt_h)
{
    __shared__ alignas(16) _Float16 smem[64 * 72 + 128 * 72];
    _Float16* As = smem;
    _Float16* Bs = smem + 64 * 72;

    int bid = blockIdx.x;
    const _Float16 *A, *Bm;
    _Float16* Out;
    long sA, sB, sOut;
    int N, tilesN, t;
    const int Kd = 128;
    if (bid < 256)      { A = Wx_h;  sA = 0;            Bm = drug_h; sB = (long)LD * DD; Out = Wxd_h; sOut = (long)KK * LD; N = LD;  tilesN = 4; t = bid; }
    else if (bid < 768) { A = Wp_h;  sA = 0;            Bm = targ_h; sB = (long)LP * DD; Out = Wpt_h; sOut = (long)KK * LP; N = LP;  tilesN = 8; t = bid - 256; }
    else                { A = targ_h; sA = (long)LP * DD; Bm = WbT_h; sB = 0;            Out = tb_h;  sOut = (long)LP * DD; N = 128; tilesN = 1; t = bid - 768; }

    int tpb = (tilesN == 1) ? 16 : tilesN;      // tb: 16 m-tiles; others: tilesN n-tiles
    int b = t / tpb;
    int q = t % tpb;
    int m0 = (tilesN == 1) ? q * 64 : 0;
    int n0 = (tilesN == 1) ? 0 : q * 128;

    const _Float16* Ab = A + (long)b * sA;
    const _Float16* Bb = Bm + (long)b * sB;

    int tid = threadIdx.x;
    int lane = tid & 63;
    int wid = tid >> 6;
    int wm = wid & 1, wn = wid >> 1;

    f32x4 acc[2][4];
#pragma unroll
    for (int i = 0; i < 2; i++)
#pragma unroll
        for (int j = 0; j < 4; j++) acc[i][j] = (f32x4)(0.0f);

    for (int k0 = 0; k0 < Kd; k0 += 64) {
#pragma unroll
        for (int i = 0; i < 2; i++) {
            int c = tid + i * 256;
            int row = c >> 3, col = c & 7;
            int4 v = *reinterpret_cast<const int4*>(Ab + (long)(m0 + row) * Kd + k0 + col * 8);
            *reinterpret_cast<int4*>(&As[row * 72 + col * 8]) = v;
        }
#pragma unroll
        for (int i = 0; i < 4; i++) {
            int c = tid + i * 256;
            int row = c >> 3, col = c & 7;
            int4 v = *reinterpret_cast<const int4*>(Bb + (long)(n0 + row) * Kd + k0 + col * 8);
            *reinterpret_cast<int4*>(&Bs[row * 72 + col * 8]) = v;
        }
        __syncthreads();
#pragma unroll
        for (int kk = 0; kk < 64; kk += 32) {
            int klane = kk + 8 * (lane >> 4);
            half8 af[2], bfr[4];
#pragma unroll
            for (int fm = 0; fm < 2; fm++)
                af[fm] = *reinterpret_cast<const half8*>(&As[(wm * 32 + fm * 16 + (lane & 15)) * 72 + klane]);
#pragma unroll
            for (int fn = 0; fn < 4; fn++)
                bfr[fn] = *reinterpret_cast<const half8*>(&Bs[(wn * 64 + fn * 16 + (lane & 15)) * 72 + klane]);
#pragma unroll
            for (int fm = 0; fm < 2; fm++)
#pragma unroll
                for (int fn = 0; fn < 4; fn++)
                    acc[fm][fn] = __builtin_amdgcn_mfma_f32_16x16x32_f16(af[fm], bfr[fn], acc[fm][fn], 0, 0, 0);
        }
        __syncthreads();
    }

    long ob = (long)b * sOut;
#pragma unroll
    for (int fm = 0; fm < 2; fm++)
#pragma unroll
        for (int fn = 0; fn < 4; fn++)
#pragma unroll
            for (int r = 0; r < 4; r++) {
                int row = m0 + wm * 32 + fm * 16 + (lane >> 4) * 4 + r;
                int col = n0 + wn * 64 + fn * 16 + (lane & 15);
                Out[ob + (long)row * N + col] = (_Float16)acc[fm][fn][r];
            }
}

// ---------------- fused C + H + score kernel (both sides, XCD-swizzled) ----------------
// side C (P < 512):  sc_c[b,n0+j] = sum_k whx[k]*tanh(Wxd[k,n0+j] + sum_p Wpt[k,p]*C[p,n0+j])
// side P (P >= 512): sc_p[b,n0+j] = sum_k whp[k]*tanh(Wpt[k,n0+j] + sum_l Wxd[k,l]*C[n0+j,l])
// XCD swizzle (T1): all tile-blocks of a batch share one XCD.
// GEMM1 operand-SWAPPED: a1 = mfma(S_frag, R_frag) -> D col=res, row=strm
//   => lane holds 4 consecutive strm at fixed res => Cts scatter is 4x half4 (8B) stores.
__global__ __launch_bounds__(256)
void k_score_fused(const _Float16* __restrict__ drug_h, const _Float16* __restrict__ tb_h,
                   const _Float16* __restrict__ Wxd_h, const _Float16* __restrict__ Wpt_h,
                   const float* __restrict__ whx, const float* __restrict__ whp,
                   float* __restrict__ sc_c, float* __restrict__ sc_p)
{
    __shared__ alignas(16) _Float16 Ss[64 * 136];   // streamed [64][128+8]
    __shared__ alignas(16) _Float16 Ws[64 * 72];    // W slice  [64k][64+8]
    __shared__ alignas(16) _Float16 Cts[64 * 72];   // C tile   [64res][64strm+8]
    __shared__ float sred[8 * 64];
    __shared__ float wsh[64];

    int P = blockIdx.x;
    int tid = threadIdx.x;
    int lane = tid & 63;
    int wid = tid >> 6;
    int wm = wid & 1, wn = wid >> 1;

    int b, n0, nsteps, Ntot, sW;
    const _Float16 *R, *S, *W, *Add;
    const float* wv;
    float* out;
    if (P < 512) {
        int x = P & 7, j = P >> 3;            // x: XCD chunk; j in [0,64)
        b = x * 8 + (j >> 3);
        n0 = (j & 7) * 64;
        R = drug_h + (long)b * (LD * DD);
        S = tb_h   + (long)b * (LP * DD);
        W = Wpt_h  + (long)b * (KK * LP);  sW = LP;
        Add = Wxd_h + (long)b * (KK * LD); Ntot = LD;
        nsteps = LP / 64; wv = whx; out = sc_c + (long)b * LD;
    } else {
        int Q = P - 512;
        int x = Q & 7, j = Q >> 3;            // j in [0,128)
        b = x * 8 + (j >> 4);
        n0 = (j & 15) * 64;
        R = tb_h   + (long)b * (LP * DD);
        S = drug_h + (long)b * (LD * DD);
        W = Wxd_h  + (long)b * (KK * LD);  sW = LD;
        Add = Wpt_h + (long)b * (KK * LP); Ntot = LP;
        nsteps = LD / 64; wv = whp; out = sc_p + (long)b * LP;
    }

    // resident fragments in registers (used as MFMA B-operand; layout symmetric)
    half8 af[2][4];
#pragma unroll
    for (int fm = 0; fm < 2; fm++)
#pragma unroll
        for (int kk = 0; kk < 4; kk++) {
            int row = n0 + wm * 32 + fm * 16 + (lane & 15);
            int col = kk * 32 + 8 * (lane >> 4);
            af[fm][kk] = *reinterpret_cast<const half8*>(R + (long)row * DD + col);
        }
    if (tid < 64) wsh[tid] = wv[tid];

    f32x4 acc2[2][2];
#pragma unroll
    for (int i = 0; i < 2; i++)
#pragma unroll
        for (int j = 0; j < 2; j++) acc2[i][j] = (f32x4)(0.0f);

    for (int s = 0; s < nsteps; s++) {
        __syncthreads();                  // (C) prev GEMM2 done; Ss/Ws/Cts free
        // stage stream tile [64][128]
#pragma unroll
        for (int i = 0; i < 4; i++) {
            int c = tid + i * 256;
            int row = c >> 4, col8 = (c & 15) * 8;
            int4 v = *reinterpret_cast<const int4*>(S + (long)(s * 64 + row) * DD + col8);
            *reinterpret_cast<int4*>(&Ss[row * 136 + col8]) = v;
        }
        // stage W slice [64][64]
#pragma unroll
        for (int i = 0; i < 2; i++) {
            int c = tid + i * 256;
            int row = c >> 3, col8 = (c & 7) * 8;
            int4 v = *reinterpret_cast<const int4*>(W + (long)row * sW + s * 64 + col8);
            *reinterpret_cast<int4*>(&Ws[row * 72 + col8]) = v;
        }
        __syncthreads();                  // (A) staging visible (covers wsh at s=0)

        // GEMM1 (swapped): a1[fn][fm] = mfma(S_frag, R_frag)
        //   D: res = wm*32+fm*16+(lane&15), strm = wn*32+fn*16+4*(lane>>4)+r
        f32x4 a1[2][2];
#pragma unroll
        for (int i = 0; i < 2; i++)
#pragma unroll
            for (int j = 0; j < 2; j++) a1[i][j] = (f32x4)(0.0f);
#pragma unroll
        for (int kk = 0; kk < 4; kk++) {
            int klane = kk * 32 + 8 * (lane >> 4);
            half8 bf[2];
#pragma unroll
            for (int fn = 0; fn < 2; fn++)
                bf[fn] = *reinterpret_cast<const half8*>(&Ss[(wn * 32 + fn * 16 + (lane & 15)) * 136 + klane]);
#pragma unroll
            for (int fn = 0; fn < 2; fn++)
#pragma unroll
                for (int fm = 0; fm < 2; fm++)
                    a1[fn][fm] = __builtin_amdgcn_mfma_f32_16x16x32_f16(bf[fn], af[fm][kk], a1[fn][fm], 0, 0, 0);
        }
        // tanh -> Cts [res][strm]: 4 contiguous strm per (fn,fm) -> half4 store
#pragma unroll
        for (int fn = 0; fn < 2; fn++)
#pragma unroll
            for (int fm = 0; fm < 2; fm++) {
                int res   = wm * 32 + fm * 16 + (lane & 15);
                int strm0 = wn * 32 + fn * 16 + 4 * (lane >> 4);
                half4 hv;
                hv.x = (_Float16)ftanh(a1[fn][fm][0]);
                hv.y = (_Float16)ftanh(a1[fn][fm][1]);
                hv.z = (_Float16)ftanh(a1[fn][fm][2]);
                hv.w = (_Float16)ftanh(a1[fn][fm][3]);
                *reinterpret_cast<half4*>(&Cts[res * 72 + strm0]) = hv;
            }
        __syncthreads();                  // (B) Cts ready

        // GEMM2: acc2[k, res] += sum_strm Ws[k,strm]*Cts[res,strm]
#pragma unroll
        for (int kk = 0; kk < 2; kk++) {
            int klane = kk * 32 + 8 * (lane >> 4);
            half8 aw[2], bf2[2];
#pragma unroll
            for (int fm = 0; fm < 2; fm++)
                aw[fm] = *reinterpret_cast<const half8*>(&Ws[(wm * 32 + fm * 16 + (lane & 15)) * 72 + klane]);
#pragma unroll
            for (int fn = 0; fn < 2; fn++)
                bf2[fn] = *reinterpret_cast<const half8*>(&Cts[(wn * 32 + fn * 16 + (lane & 15)) * 72 + klane]);
#pragma unroll
            for (int fm = 0; fm < 2; fm++)
#pragma unroll
                for (int fn = 0; fn < 2; fn++)
                    acc2[fm][fn] = __builtin_amdgcn_mfma_f32_16x16x32_f16(aw[fm], bf2[fn], acc2[fm][fn], 0, 0, 0);
        }
    }

    // epilogue: + Add, tanh, dot w, block reduce over k
    float ps[2] = {0.f, 0.f};
#pragma unroll
    for (int fm = 0; fm < 2; fm++)
#pragma unroll
        for (int fn = 0; fn < 2; fn++)
#pragma unroll
            for (int r = 0; r < 4; r++) {
                int k   = wm * 32 + fm * 16 + (lane >> 4) * 4 + r;
                int col = wn * 32 + fn * 16 + (lane & 15);
                float v = ftanh(acc2[fm][fn][r] + (float)Add[(long)k * Ntot + n0 + col]);
                ps[fn] += wsh[k] * v;
            }
#pragma unroll
    for (int fn = 0; fn < 2; fn++)
        sred[(wm * 4 + (lane >> 4)) * 64 + wn * 32 + fn * 16 + (lane & 15)] = ps[fn];
    __syncthreads();
    if (tid < 64) {
        float sacc = 0.f;
#pragma unroll
        for (int j = 0; j < 8; j++) sacc += sred[j * 64 + tid];
        out[n0 + tid] = sacc;
    }
}

// ---------------- softmax over scores ----------------
__device__ __forceinline__ float wred_max(float v) {
#pragma unroll
    for (int off = 32; off > 0; off >>= 1) v = fmaxf(v, __shfl_xor(v, off, 64));
    return v;
}
__device__ __forceinline__ float wred_sum(float v) {
#pragma unroll
    for (int off = 32; off > 0; off >>= 1) v += __shfl_xor(v, off, 64);
    return v;
}

__global__ __launch_bounds__(1024)
void k_soft(const float* __restrict__ scc, const float* __restrict__ scp,
            float* __restrict__ ac, float* __restrict__ ap)
{
    __shared__ float r16[16];
    int b = blockIdx.x, tid = threadIdx.x;
    int lane = tid & 63, wid = tid >> 6;

    float s = (tid < 512) ? scc[b * 512 + tid] : -3.4e38f;
    float m = wred_max(s);
    if (lane == 0) r16[wid] = m;
    __syncthreads();
    m = r16[0];
#pragma unroll
    for (int i = 1; i < 16; i++) m = fmaxf(m, r16[i]);
    float e = (tid < 512) ? __expf(s - m) : 0.f;
    __syncthreads();
    float t = wred_sum(e);
    if (lane == 0) r16[wid] = t;
    __syncthreads();
    float sum = 0.f;
#pragma unroll
    for (int i = 0; i < 16; i++) sum += r16[i];
    if (tid < 512) ac[b * 512 + tid] = e * __builtin_amdgcn_rcpf(sum);
    __syncthreads();

    float s2 = scp[b * 1024 + tid];
    float m2 = wred_max(s2);
    if (lane == 0) r16[wid] = m2;
    __syncthreads();
    m2 = r16[0];
#pragma unroll
    for (int i = 1; i < 16; i++) m2 = fmaxf(m2, r16[i]);
    float e2 = __expf(s2 - m2);
    __syncthreads();
    float t2 = wred_sum(e2);
    if (lane == 0) r16[wid] = t2;
    __syncthreads();
    float sum2 = 0.f;
#pragma unroll
    for (int i = 0; i < 16; i++) sum2 += r16[i];
    ap[b * 1024 + tid] = e2 * __builtin_amdgcn_rcpf(sum2);
}

// ---------------- weighted sums: out[b,d] = sum_l a[l] * X[b,l,d] ----------------
__global__ __launch_bounds__(512)
void k_wsum(const _Float16* __restrict__ drug_h, const _Float16* __restrict__ targ_h,
            const float* __restrict__ ac, const float* __restrict__ ap,
            float* __restrict__ out)
{
    __shared__ float ash[1024];
    __shared__ float red[32 * 128];
    int b = blockIdx.x, side = blockIdx.y;
    int L = side ? LP : LD;
    const _Float16* X = side ? targ_h : drug_h;
    const float* a = side ? ap : ac;
    float* ob = out + side * 8192 + b * 128;
    int tid = threadIdx.x;

    for (int i = tid; i < L; i += 512) ash[i] = a[(long)b * L + i];
    __syncthreads();

    int col8 = tid & 15, rg = tid >> 4;
    float accv[8];
#pragma unroll
    for (int j = 0; j < 8; j++) accv[j] = 0.f;
    const _Float16* Xb = X + (long)b * L * 128;
    for (int l = rg; l < L; l += 32) {
        half8 v = *reinterpret_cast<const half8*>(&Xb[l * 128 + col8 * 8]);
        float av = ash[l];
#pragma unroll
        for (int j = 0; j < 8; j++) accv[j] += av * (float)v[j];
    }
#pragma unroll
    for (int j = 0; j < 8; j++) red[rg * 128 + col8 * 8 + j] = accv[j];
    __syncthreads();
    if (tid < 128) {
        float s = 0.f;
#pragma unroll
        for (int g = 0; g < 32; g++) s += red[g * 128 + tid];
        ob[tid] = s;
    }
}

// ---------------- launch ----------------
extern "C" void kernel_launch(void* const* d_in, const int* in_sizes, int n_in,
                              void* d_out, int out_size, void* d_ws, size_t ws_size,
                              hipStream_t stream) {
    (void)in_sizes; (void)n_in; (void)out_size;
    const float* drug   = (const float*)d_in[0];
    const float* target = (const float*)d_in[1];
    const float* Wb     = (const float*)d_in[2];
    const float* Wx     = (const float*)d_in[3];
    const float* Wp     = (const float*)d_in[4];
    const float* whx    = (const float*)d_in[5];
    const float* whp    = (const float*)d_in[6];

    char* w = (char*)d_ws;
    size_t off = 0;
    auto takeb = [&](size_t bytes) {
        void* p = (void*)(w + off);
        off += (bytes + 255) & ~(size_t)255;
        return p;
    };
    _Float16* drug_h = (_Float16*)takeb((size_t)NB * LD * DD * 2);
    _Float16* targ_h = (_Float16*)takeb((size_t)NB * LP * DD * 2);
    _Float16* WbT_h  = (_Float16*)takeb(128 * 128 * 2);
    _Float16* Wx_h   = (_Float16*)takeb(64 * 128 * 2);
    _Float16* Wp_h   = (_Float16*)takeb(64 * 128 * 2);
    _Float16* tb_h   = (_Float16*)takeb((size_t)NB * LP * DD * 2);
    _Float16* Wxd_h  = (_Float16*)takeb((size_t)NB * KK * LD * 2);
    _Float16* Wpt_h  = (_Float16*)takeb((size_t)NB * KK * LP * 2);
    float*    sc_c   = (float*)takeb((size_t)NB * LD * 4);
    float*    sc_p   = (float*)takeb((size_t)NB * LP * 4);
    float*    a_c    = (float*)takeb((size_t)NB * LD * 4);
    float*    a_p    = (float*)takeb((size_t)NB * LP * 4);

    if (off > ws_size) {                 // workspace shortfall -> sentinel (absmax ~1000)
        k_sentinel<<<1, 64, 0, stream>>>((float*)d_out);
        return;
    }

    k_conv<<<1024, 256, 0, stream>>>(drug,   drug_h, NB * LD * DD);
    k_conv<<<1024, 256, 0, stream>>>(target, targ_h, NB * LP * DD);
    k_prep<<<80, 256, 0, stream>>>(Wb, WbT_h, Wx, Wx_h, Wp, Wp_h);

    // merged: Wxd + Wpt + tb in one dispatch
    k_gemm3<<<dim3(1792), 256, 0, stream>>>(
        drug_h, targ_h, WbT_h, Wx_h, Wp_h, tb_h, Wxd_h, Wpt_h);

    // fused: C recomputed per side in-LDS; scores out directly
    k_score_fused<<<dim3(512 + 1024), 256, 0, stream>>>(
        drug_h, tb_h, Wxd_h, Wpt_h, whx, whp, sc_c, sc_p);

    k_soft<<<NB, 1024, 0, stream>>>(sc_c, sc_p, a_c, a_p);
    k_wsum<<<dim3(NB, 2), 512, 0, stream>>>(drug_h, targ_h, a_c, a_p, (float*)d_out);
}

// Round 17
// 87.836 us; speedup vs baseline: 1.8006x; 1.1673x over previous
//
#include <hip/hip_runtime.h>
#include <hip/hip_bf16.h>
#include <math.h>

#define NB 64
#define LD 512
#define LP 1024
#define DD 128
#define KK 64

using half8 = __attribute__((ext_vector_type(8))) _Float16;
using half4 = __attribute__((ext_vector_type(4))) _Float16;
using f32x4 = __attribute__((ext_vector_type(4))) float;

// fast tanh: 1 - 2*rcp(e^{2x}+1) via v_rcp_f32 (no IEEE div sequence).
__device__ __forceinline__ float ftanh(float x) {
    float e = __expf(2.0f * x);
    return 1.0f - 2.0f * __builtin_amdgcn_rcpf(e + 1.0f);
}

// ---------------- conversion kernels ----------------
__global__ void k_conv(const float* __restrict__ in, _Float16* __restrict__ out, int n) {
    int i = (blockIdx.x * blockDim.x + threadIdx.x) * 4;
    int stride = gridDim.x * blockDim.x * 4;
    for (; i < n; i += stride) {
        float4 v = *reinterpret_cast<const float4*>(in + i);
        half4 h;
        h.x = (_Float16)v.x; h.y = (_Float16)v.y; h.z = (_Float16)v.z; h.w = (_Float16)v.w;
        *reinterpret_cast<half4*>(out + i) = h;
    }
}

// merged small preps: blocks 0-63 WbT transpose, 64-71 Wx conv, 72-79 Wp conv
__global__ void k_prep(const float* __restrict__ Wb, _Float16* __restrict__ WbT,
                       const float* __restrict__ Wx, _Float16* __restrict__ Wx_h,
                       const float* __restrict__ Wp, _Float16* __restrict__ Wp_h)
{
    int bid = blockIdx.x, tid = threadIdx.x;
    if (bid < 64) {
        int t = bid * 256 + tid;
        int d = t >> 7, e = t & 127;
        WbT[t] = (_Float16)Wb[e * 128 + d];
    } else {
        const float* src = (bid < 72) ? Wx : Wp;
        _Float16* dst = (bid < 72) ? Wx_h : Wp_h;
        int i = ((bid & 7) * 256 + tid) * 4;
        float4 v = *reinterpret_cast<const float4*>(src + i);
        half4 h;
        h.x = (_Float16)v.x; h.y = (_Float16)v.y; h.z = (_Float16)v.z; h.w = (_Float16)v.w;
        *reinterpret_cast<half4*>(dst + i) = h;
    }
}

__global__ void k_sentinel(float* out) {
    if (threadIdx.x == 0 && blockIdx.x == 0) out[0] = 1000.0f;
}

// ---------------- merged NT GEMM dispatch: Wxd + Wpt + tb in one grid ----------------
// ranges: [0,256) Wxd ; [256,768) Wpt ; [768,1792) tb
__global__ __launch_bounds__(256)
void k_gemm3(const _Float16* __restrict__ drug_h, const _Float16* __restrict__ targ_h,
             const _Float16* __restrict__ WbT_h, const _Float16* __restrict__ Wx_h,
             const _Float16* __restrict__ Wp_h,
             _Float16* __restrict__ tb_h, _Float16* __restrict__ Wxd_h,
             _Float16* __restrict__ Wpt_h)
{
    __shared__ alignas(16) _Float16 smem[64 * 72 + 128 * 72];
    _Float16* As = smem;
    _Float16* Bs = smem + 64 * 72;

    int bid = blockIdx.x;
    const _Float16 *A, *Bm;
    _Float16* Out;
    long sA, sB, sOut;
    int N, tilesN, t;
    const int Kd = 128;
    if (bid < 256)      { A = Wx_h;  sA = 0;            Bm = drug_h; sB = (long)LD * DD; Out = Wxd_h; sOut = (long)KK * LD; N = LD;  tilesN = 4; t = bid; }
    else if (bid < 768) { A = Wp_h;  sA = 0;            Bm = targ_h; sB = (long)LP * DD; Out = Wpt_h; sOut = (long)KK * LP; N = LP;  tilesN = 8; t = bid - 256; }
    else                { A = targ_h; sA = (long)LP * DD; Bm = WbT_h; sB = 0;            Out = tb_h;  sOut = (long)LP * DD; N = 128; tilesN = 1; t = bid - 768; }

    int tpb = (tilesN == 1) ? 16 : tilesN;
    int b = t / tpb;
    int q = t % tpb;
    int m0 = (tilesN == 1) ? q * 64 : 0;
    int n0 = (tilesN == 1) ? 0 : q * 128;

    const _Float16* Ab = A + (long)b * sA;
    const _Float16* Bb = Bm + (long)b * sB;

    int tid = threadIdx.x;
    int lane = tid & 63;
    int wid = tid >> 6;
    int wm = wid & 1, wn = wid >> 1;

    f32x4 acc[2][4];
#pragma unroll
    for (int i = 0; i < 2; i++)
#pragma unroll
        for (int j = 0; j < 4; j++) acc[i][j] = (f32x4)(0.0f);

    for (int k0 = 0; k0 < Kd; k0 += 64) {
#pragma unroll
        for (int i = 0; i < 2; i++) {
            int c = tid + i * 256;
            int row = c >> 3, col = c & 7;
            int4 v = *reinterpret_cast<const int4*>(Ab + (long)(m0 + row) * Kd + k0 + col * 8);
            *reinterpret_cast<int4*>(&As[row * 72 + col * 8]) = v;
        }
#pragma unroll
        for (int i = 0; i < 4; i++) {
            int c = tid + i * 256;
            int row = c >> 3, col = c & 7;
            int4 v = *reinterpret_cast<const int4*>(Bb + (long)(n0 + row) * Kd + k0 + col * 8);
            *reinterpret_cast<int4*>(&Bs[row * 72 + col * 8]) = v;
        }
        __syncthreads();
#pragma unroll
        for (int kk = 0; kk < 64; kk += 32) {
            int klane = kk + 8 * (lane >> 4);
            half8 af[2], bfr[4];
#pragma unroll
            for (int fm = 0; fm < 2; fm++)
                af[fm] = *reinterpret_cast<const half8*>(&As[(wm * 32 + fm * 16 + (lane & 15)) * 72 + klane]);
#pragma unroll
            for (int fn = 0; fn < 4; fn++)
                bfr[fn] = *reinterpret_cast<const half8*>(&Bs[(wn * 64 + fn * 16 + (lane & 15)) * 72 + klane]);
#pragma unroll
            for (int fm = 0; fm < 2; fm++)
#pragma unroll
                for (int fn = 0; fn < 4; fn++)
                    acc[fm][fn] = __builtin_amdgcn_mfma_f32_16x16x32_f16(af[fm], bfr[fn], acc[fm][fn], 0, 0, 0);
        }
        __syncthreads();
    }

    long ob = (long)b * sOut;
#pragma unroll
    for (int fm = 0; fm < 2; fm++)
#pragma unroll
        for (int fn = 0; fn < 4; fn++)
#pragma unroll
            for (int r = 0; r < 4; r++) {
                int row = m0 + wm * 32 + fm * 16 + (lane >> 4) * 4 + r;
                int col = n0 + wn * 64 + fn * 16 + (lane & 15);
                Out[ob + (long)row * N + col] = (_Float16)acc[fm][fn][r];
            }
}

// ---------------- fused C + H + score kernel, RES=128 (both sides, XCD-swizzled) ----
// side C (P < 256):  res = drug l (128 rows), stream = tb p; nsteps=16
// side P (P >= 256): res = tb p (128 rows), stream = drug l; nsteps=8
// 768 blocks = exactly 3/CU (LDS 49.4 KB); all co-resident, zero tail.
// GEMM1 swapped: a1 = mfma(S_frag, R_frag) -> D col=res, row=strm (half4 scatter).
__global__ __launch_bounds__(256, 3)
void k_score_fused(const _Float16* __restrict__ drug_h, const _Float16* __restrict__ tb_h,
                   const _Float16* __restrict__ Wxd_h, const _Float16* __restrict__ Wpt_h,
                   const float* __restrict__ whx, const float* __restrict__ whp,
                   float* __restrict__ sc_c, float* __restrict__ sc_p)
{
    __shared__ alignas(16) _Float16 Ss[64 * 136];   // streamed [64][128+8]
    __shared__ alignas(16) _Float16 Ws[64 * 72];    // W slice  [64k][64+8]
    __shared__ alignas(16) _Float16 Cts[128 * 72];  // C tile   [128res][64strm+8]
    __shared__ float sred[8 * 128];
    __shared__ float wsh[64];

    int P = blockIdx.x;
    int tid = threadIdx.x;
    int lane = tid & 63;
    int wid = tid >> 6;
    int wm = wid & 1, wn = wid >> 1;

    int b, n0, nsteps, Ntot, sW;
    const _Float16 *R, *S, *W, *Add;
    const float* wv;
    float* out;
    if (P < 256) {
        int x = P & 7, j = P >> 3;            // j in [0,32)
        b = x * 8 + (j >> 2);                  // batches [8x,8x+8) on XCD x
        n0 = (j & 3) * 128;
        R = drug_h + (long)b * (LD * DD);
        S = tb_h   + (long)b * (LP * DD);
        W = Wpt_h  + (long)b * (KK * LP);  sW = LP;
        Add = Wxd_h + (long)b * (KK * LD); Ntot = LD;
        nsteps = LP / 64; wv = whx; out = sc_c + (long)b * LD;
    } else {
        int Q = P - 256;
        int x = Q & 7, j = Q >> 3;            // j in [0,64)
        b = x * 8 + (j >> 3);
        n0 = (j & 7) * 128;
        R = tb_h   + (long)b * (LP * DD);
        S = drug_h + (long)b * (LD * DD);
        W = Wxd_h  + (long)b * (KK * LD);  sW = LD;
        Add = Wpt_h + (long)b * (KK * LP); Ntot = LP;
        nsteps = LD / 64; wv = whp; out = sc_p + (long)b * LP;
    }

    // resident fragments in registers (MFMA B-operand): 128 rows = wm*64 + fm*16 + (lane&15)
    half8 af[4][4];
#pragma unroll
    for (int fm = 0; fm < 4; fm++)
#pragma unroll
        for (int kk = 0; kk < 4; kk++) {
            int row = n0 + wm * 64 + fm * 16 + (lane & 15);
            int col = kk * 32 + 8 * (lane >> 4);
            af[fm][kk] = *reinterpret_cast<const half8*>(R + (long)row * DD + col);
        }
    if (tid < 64) wsh[tid] = wv[tid];

    f32x4 acc2[2][4];
#pragma unroll
    for (int i = 0; i < 2; i++)
#pragma unroll
        for (int j = 0; j < 4; j++) acc2[i][j] = (f32x4)(0.0f);

    for (int s = 0; s < nsteps; s++) {
        __syncthreads();                  // (C) prev GEMM2 done; Ss/Ws/Cts free
        // stage stream tile [64][128]
#pragma unroll
        for (int i = 0; i < 4; i++) {
            int c = tid + i * 256;
            int row = c >> 4, col8 = (c & 15) * 8;
            int4 v = *reinterpret_cast<const int4*>(S + (long)(s * 64 + row) * DD + col8);
            *reinterpret_cast<int4*>(&Ss[row * 136 + col8]) = v;
        }
        // stage W slice [64][64]
#pragma unroll
        for (int i = 0; i < 2; i++) {
            int c = tid + i * 256;
            int row = c >> 3, col8 = (c & 7) * 8;
            int4 v = *reinterpret_cast<const int4*>(W + (long)row * sW + s * 64 + col8);
            *reinterpret_cast<int4*>(&Ws[row * 72 + col8]) = v;
        }
        __syncthreads();                  // (A) staging visible (covers wsh at s=0)

        // GEMM1 (swapped): a1[fn][fm] = mfma(S_frag, R_frag)
        //   D: res = wm*64+fm*16+(lane&15), strm = wn*32+fn*16+4*(lane>>4)+r
        f32x4 a1[2][4];
#pragma unroll
        for (int i = 0; i < 2; i++)
#pragma unroll
            for (int j = 0; j < 4; j++) a1[i][j] = (f32x4)(0.0f);
#pragma unroll
        for (int kk = 0; kk < 4; kk++) {
            int klane = kk * 32 + 8 * (lane >> 4);
            half8 bf[2];
#pragma unroll
            for (int fn = 0; fn < 2; fn++)
                bf[fn] = *reinterpret_cast<const half8*>(&Ss[(wn * 32 + fn * 16 + (lane & 15)) * 136 + klane]);
#pragma unroll
            for (int fn = 0; fn < 2; fn++)
#pragma unroll
                for (int fm = 0; fm < 4; fm++)
                    a1[fn][fm] = __builtin_amdgcn_mfma_f32_16x16x32_f16(bf[fn], af[fm][kk], a1[fn][fm], 0, 0, 0);
        }
        // tanh -> Cts [res][strm]: 4 contiguous strm per (fn,fm) -> half4 store
#pragma unroll
        for (int fn = 0; fn < 2; fn++)
#pragma unroll
            for (int fm = 0; fm < 4; fm++) {
                int res   = wm * 64 + fm * 16 + (lane & 15);
                int strm0 = wn * 32 + fn * 16 + 4 * (lane >> 4);
                half4 hv;
                hv.x = (_Float16)ftanh(a1[fn][fm][0]);
                hv.y = (_Float16)ftanh(a1[fn][fm][1]);
                hv.z = (_Float16)ftanh(a1[fn][fm][2]);
                hv.w = (_Float16)ftanh(a1[fn][fm][3]);
                *reinterpret_cast<half4*>(&Cts[res * 72 + strm0]) = hv;
            }
        __syncthreads();                  // (B) Cts ready

        // GEMM2: acc2[k, res] += sum_strm Ws[k,strm]*Cts[res,strm]
        //   k = wm*32+fm2*16+..., res = wn*64+fn2*16+...
#pragma unroll
        for (int kk = 0; kk < 2; kk++) {
            int klane = kk * 32 + 8 * (lane >> 4);
            half8 aw[2], bf2[4];
#pragma unroll
            for (int fm2 = 0; fm2 < 2; fm2++)
                aw[fm2] = *reinterpret_cast<const half8*>(&Ws[(wm * 32 + fm2 * 16 + (lane & 15)) * 72 + klane]);
#pragma unroll
            for (int fn2 = 0; fn2 < 4; fn2++)
                bf2[fn2] = *reinterpret_cast<const half8*>(&Cts[(wn * 64 + fn2 * 16 + (lane & 15)) * 72 + klane]);
#pragma unroll
            for (int fm2 = 0; fm2 < 2; fm2++)
#pragma unroll
                for (int fn2 = 0; fn2 < 4; fn2++)
                    acc2[fm2][fn2] = __builtin_amdgcn_mfma_f32_16x16x32_f16(aw[fm2], bf2[fn2], acc2[fm2][fn2], 0, 0, 0);
        }
    }

    // epilogue: + Add, tanh, dot w, block reduce over k
    float ps[4] = {0.f, 0.f, 0.f, 0.f};
#pragma unroll
    for (int fm2 = 0; fm2 < 2; fm2++)
#pragma unroll
        for (int fn2 = 0; fn2 < 4; fn2++)
#pragma unroll
            for (int r = 0; r < 4; r++) {
                int k   = wm * 32 + fm2 * 16 + (lane >> 4) * 4 + r;
                int col = wn * 64 + fn2 * 16 + (lane & 15);
                float v = ftanh(acc2[fm2][fn2][r] + (float)Add[(long)k * Ntot + n0 + col]);
                ps[fn2] += wsh[k] * v;
            }
#pragma unroll
    for (int fn2 = 0; fn2 < 4; fn2++)
        sred[(wm * 4 + (lane >> 4)) * 128 + wn * 64 + fn2 * 16 + (lane & 15)] = ps[fn2];
    __syncthreads();
    if (tid < 128) {
        float sacc = 0.f;
#pragma unroll
        for (int j = 0; j < 8; j++) sacc += sred[j * 128 + tid];
        out[n0 + tid] = sacc;
    }
}

// ---------------- softmax over scores ----------------
__device__ __forceinline__ float wred_max(float v) {
#pragma unroll
    for (int off = 32; off > 0; off >>= 1) v = fmaxf(v, __shfl_xor(v, off, 64));
    return v;
}
__device__ __forceinline__ float wred_sum(float v) {
#pragma unroll
    for (int off = 32; off > 0; off >>= 1) v += __shfl_xor(v, off, 64);
    return v;
}

__global__ __launch_bounds__(1024)
void k_soft(const float* __restrict__ scc, const float* __restrict__ scp,
            float* __restrict__ ac, float* __restrict__ ap)
{
    __shared__ float r16[16];
    int b = blockIdx.x, tid = threadIdx.x;
    int lane = tid & 63, wid = tid >> 6;

    float s = (tid < 512) ? scc[b * 512 + tid] : -3.4e38f;
    float m = wred_max(s);
    if (lane == 0) r16[wid] = m;
    __syncthreads();
    m = r16[0];
#pragma unroll
    for (int i = 1; i < 16; i++) m = fmaxf(m, r16[i]);
    float e = (tid < 512) ? __expf(s - m) : 0.f;
    __syncthreads();
    float t = wred_sum(e);
    if (lane == 0) r16[wid] = t;
    __syncthreads();
    float sum = 0.f;
#pragma unroll
    for (int i = 0; i < 16; i++) sum += r16[i];
    if (tid < 512) ac[b * 512 + tid] = e * __builtin_amdgcn_rcpf(sum);
    __syncthreads();

    float s2 = scp[b * 1024 + tid];
    float m2 = wred_max(s2);
    if (lane == 0) r16[wid] = m2;
    __syncthreads();
    m2 = r16[0];
#pragma unroll
    for (int i = 1; i < 16; i++) m2 = fmaxf(m2, r16[i]);
    float e2 = __expf(s2 - m2);
    __syncthreads();
    float t2 = wred_sum(e2);
    if (lane == 0) r16[wid] = t2;
    __syncthreads();
    float sum2 = 0.f;
#pragma unroll
    for (int i = 0; i < 16; i++) sum2 += r16[i];
    ap[b * 1024 + tid] = e2 * __builtin_amdgcn_rcpf(sum2);
}

// ---------------- weighted sums: out[b,d] = sum_l a[l] * X[b,l,d] ----------------
__global__ __launch_bounds__(512)
void k_wsum(const _Float16* __restrict__ drug_h, const _Float16* __restrict__ targ_h,
            const float* __restrict__ ac, const float* __restrict__ ap,
            float* __restrict__ out)
{
    __shared__ float ash[1024];
    __shared__ float red[32 * 128];
    int b = blockIdx.x, side = blockIdx.y;
    int L = side ? LP : LD;
    const _Float16* X = side ? targ_h : drug_h;
    const float* a = side ? ap : ac;
    float* ob = out + side * 8192 + b * 128;
    int tid = threadIdx.x;

    for (int i = tid; i < L; i += 512) ash[i] = a[(long)b * L + i];
    __syncthreads();

    int col8 = tid & 15, rg = tid >> 4;
    float accv[8];
#pragma unroll
    for (int j = 0; j < 8; j++) accv[j] = 0.f;
    const _Float16* Xb = X + (long)b * L * 128;
    for (int l = rg; l < L; l += 32) {
        half8 v = *reinterpret_cast<const half8*>(&Xb[l * 128 + col8 * 8]);
        float av = ash[l];
#pragma unroll
        for (int j = 0; j < 8; j++) accv[j] += av * (float)v[j];
    }
#pragma unroll
    for (int j = 0; j < 8; j++) red[rg * 128 + col8 * 8 + j] = accv[j];
    __syncthreads();
    if (tid < 128) {
        float s = 0.f;
#pragma unroll
        for (int g = 0; g < 32; g++) s += red[g * 128 + tid];
        ob[tid] = s;
    }
}

// ---------------- launch ----------------
extern "C" void kernel_launch(void* const* d_in, const int* in_sizes, int n_in,
                              void* d_out, int out_size, void* d_ws, size_t ws_size,
                              hipStream_t stream) {
    (void)in_sizes; (void)n_in; (void)out_size;
    const float* drug   = (const float*)d_in[0];
    const float* target = (const float*)d_in[1];
    const float* Wb     = (const float*)d_in[2];
    const float* Wx     = (const float*)d_in[3];
    const float* Wp     = (const float*)d_in[4];
    const float* whx    = (const float*)d_in[5];
    const float* whp    = (const float*)d_in[6];

    char* w = (char*)d_ws;
    size_t off = 0;
    auto takeb = [&](size_t bytes) {
        void* p = (void*)(w + off);
        off += (bytes + 255) & ~(size_t)255;
        return p;
    };
    _Float16* drug_h = (_Float16*)takeb((size_t)NB * LD * DD * 2);
    _Float16* targ_h = (_Float16*)takeb((size_t)NB * LP * DD * 2);
    _Float16* WbT_h  = (_Float16*)takeb(128 * 128 * 2);
    _Float16* Wx_h   = (_Float16*)takeb(64 * 128 * 2);
    _Float16* Wp_h   = (_Float16*)takeb(64 * 128 * 2);
    _Float16* tb_h   = (_Float16*)takeb((size_t)NB * LP * DD * 2);
    _Float16* Wxd_h  = (_Float16*)takeb((size_t)NB * KK * LD * 2);
    _Float16* Wpt_h  = (_Float16*)takeb((size_t)NB * KK * LP * 2);
    float*    sc_c   = (float*)takeb((size_t)NB * LD * 4);
    float*    sc_p   = (float*)takeb((size_t)NB * LP * 4);
    float*    a_c    = (float*)takeb((size_t)NB * LD * 4);
    float*    a_p    = (float*)takeb((size_t)NB * LP * 4);

    if (off > ws_size) {                 // workspace shortfall -> sentinel (absmax ~1000)
        k_sentinel<<<1, 64, 0, stream>>>((float*)d_out);
        return;
    }

    k_conv<<<1024, 256, 0, stream>>>(drug,   drug_h, NB * LD * DD);
    k_conv<<<1024, 256, 0, stream>>>(target, targ_h, NB * LP * DD);
    k_prep<<<80, 256, 0, stream>>>(Wb, WbT_h, Wx, Wx_h, Wp, Wp_h);

    // merged: Wxd + Wpt + tb in one dispatch
    k_gemm3<<<dim3(1792), 256, 0, stream>>>(
        drug_h, targ_h, WbT_h, Wx_h, Wp_h, tb_h, Wxd_h, Wpt_h);

    // fused: C recomputed per side in-LDS; scores out directly (RES=128, 768 blocks)
    k_score_fused<<<dim3(256 + 512), 256, 0, stream>>>(
        drug_h, tb_h, Wxd_h, Wpt_h, whx, whp, sc_c, sc_p);

    k_soft<<<NB, 1024, 0, stream>>>(sc_c, sc_p, a_c, a_p);
    k_wsum<<<dim3(NB, 2), 512, 0, stream>>>(drug_h, targ_h, a_c, a_p, (float*)d_out);
}

// Round 18
// 83.890 us; speedup vs baseline: 1.8853x; 1.0470x over previous
//
#include <hip/hip_runtime.h>
#include <hip/hip_bf16.h>
#include <math.h>

#define NB 64
#define LD 512
#define LP 1024
#define DD 128
#define KK 64

using half8 = __attribute__((ext_vector_type(8))) _Float16;
using half4 = __attribute__((ext_vector_type(4))) _Float16;
using f32x4 = __attribute__((ext_vector_type(4))) float;

// fast tanh: 1 - 2*rcp(e^{2x}+1) via v_rcp_f32 (no IEEE div sequence).
__device__ __forceinline__ float ftanh(float x) {
    float e = __expf(2.0f * x);
    return 1.0f - 2.0f * __builtin_amdgcn_rcpf(e + 1.0f);
}

__global__ void k_sentinel(float* out) {
    if (threadIdx.x == 0 && blockIdx.x == 0) out[0] = 1000.0f;
}

// ---------------- merged front-end: drug conv + targ conv + WbT + Wx/Wp ----------------
// [0,1024) drug conv ; [1024,2048) targ conv ; [2048,2112) WbT ; [2112,2128) Wx/Wp
__global__ void k_convprep(const float* __restrict__ drug, _Float16* __restrict__ drug_h,
                           const float* __restrict__ targ, _Float16* __restrict__ targ_h,
                           const float* __restrict__ Wb, _Float16* __restrict__ WbT,
                           const float* __restrict__ Wx, _Float16* __restrict__ Wx_h,
                           const float* __restrict__ Wp, _Float16* __restrict__ Wp_h)
{
    int bid = blockIdx.x, tid = threadIdx.x;
    if (bid < 2048) {
        const float* in = (bid < 1024) ? drug : targ;
        _Float16* out = (bid < 1024) ? drug_h : targ_h;
        int n = (bid < 1024) ? (NB * LD * DD) : (NB * LP * DD);
        int blk = bid & 1023;
        int i = (blk * 256 + tid) * 4;
        int stride = 1024 * 256 * 4;
        for (; i < n; i += stride) {
            float4 v = *reinterpret_cast<const float4*>(in + i);
            half4 h;
            h.x = (_Float16)v.x; h.y = (_Float16)v.y; h.z = (_Float16)v.z; h.w = (_Float16)v.w;
            *reinterpret_cast<half4*>(out + i) = h;
        }
    } else if (bid < 2112) {
        int t = (bid - 2048) * 256 + tid;
        int d = t >> 7, e = t & 127;
        WbT[t] = (_Float16)Wb[e * 128 + d];
    } else {
        int q = bid - 2112;
        const float* src = (q < 8) ? Wx : Wp;
        _Float16* dst = (q < 8) ? Wx_h : Wp_h;
        int i = ((q & 7) * 256 + tid) * 4;
        float4 v = *reinterpret_cast<const float4*>(src + i);
        half4 h;
        h.x = (_Float16)v.x; h.y = (_Float16)v.y; h.z = (_Float16)v.z; h.w = (_Float16)v.w;
        *reinterpret_cast<half4*>(dst + i) = h;
    }
}

// ---------------- merged NT GEMM dispatch: Wxd + Wpt + tb in one grid ----------------
// ranges: [0,256) Wxd ; [256,768) Wpt ; [768,1792) tb
__global__ __launch_bounds__(256)
void k_gemm3(const _Float16* __restrict__ drug_h, const _Float16* __restrict__ targ_h,
             const _Float16* __restrict__ WbT_h, const _Float16* __restrict__ Wx_h,
             const _Float16* __restrict__ Wp_h,
             _Float16* __restrict__ tb_h, _Float16* __restrict__ Wxd_h,
             _Float16* __restrict__ Wpt_h)
{
    __shared__ alignas(16) _Float16 smem[64 * 72 + 128 * 72];
    _Float16* As = smem;
    _Float16* Bs = smem + 64 * 72;

    int bid = blockIdx.x;
    const _Float16 *A, *Bm;
    _Float16* Out;
    long sA, sB, sOut;
    int N, tilesN, t;
    const int Kd = 128;
    if (bid < 256)      { A = Wx_h;  sA = 0;            Bm = drug_h; sB = (long)LD * DD; Out = Wxd_h; sOut = (long)KK * LD; N = LD;  tilesN = 4; t = bid; }
    else if (bid < 768) { A = Wp_h;  sA = 0;            Bm = targ_h; sB = (long)LP * DD; Out = Wpt_h; sOut = (long)KK * LP; N = LP;  tilesN = 8; t = bid - 256; }
    else                { A = targ_h; sA = (long)LP * DD; Bm = WbT_h; sB = 0;            Out = tb_h;  sOut = (long)LP * DD; N = 128; tilesN = 1; t = bid - 768; }

    int tpb = (tilesN == 1) ? 16 : tilesN;
    int b = t / tpb;
    int q = t % tpb;
    int m0 = (tilesN == 1) ? q * 64 : 0;
    int n0 = (tilesN == 1) ? 0 : q * 128;

    const _Float16* Ab = A + (long)b * sA;
    const _Float16* Bb = Bm + (long)b * sB;

    int tid = threadIdx.x;
    int lane = tid & 63;
    int wid = tid >> 6;
    int wm = wid & 1, wn = wid >> 1;

    f32x4 acc[2][4];
#pragma unroll
    for (int i = 0; i < 2; i++)
#pragma unroll
        for (int j = 0; j < 4; j++) acc[i][j] = (f32x4)(0.0f);

    for (int k0 = 0; k0 < Kd; k0 += 64) {
#pragma unroll
        for (int i = 0; i < 2; i++) {
            int c = tid + i * 256;
            int row = c >> 3, col = c & 7;
            int4 v = *reinterpret_cast<const int4*>(Ab + (long)(m0 + row) * Kd + k0 + col * 8);
            *reinterpret_cast<int4*>(&As[row * 72 + col * 8]) = v;
        }
#pragma unroll
        for (int i = 0; i < 4; i++) {
            int c = tid + i * 256;
            int row = c >> 3, col = c & 7;
            int4 v = *reinterpret_cast<const int4*>(Bb + (long)(n0 + row) * Kd + k0 + col * 8);
            *reinterpret_cast<int4*>(&Bs[row * 72 + col * 8]) = v;
        }
        __syncthreads();
#pragma unroll
        for (int kk = 0; kk < 64; kk += 32) {
            int klane = kk + 8 * (lane >> 4);
            half8 af[2], bfr[4];
#pragma unroll
            for (int fm = 0; fm < 2; fm++)
                af[fm] = *reinterpret_cast<const half8*>(&As[(wm * 32 + fm * 16 + (lane & 15)) * 72 + klane]);
#pragma unroll
            for (int fn = 0; fn < 4; fn++)
                bfr[fn] = *reinterpret_cast<const half8*>(&Bs[(wn * 64 + fn * 16 + (lane & 15)) * 72 + klane]);
#pragma unroll
            for (int fm = 0; fm < 2; fm++)
#pragma unroll
                for (int fn = 0; fn < 4; fn++)
                    acc[fm][fn] = __builtin_amdgcn_mfma_f32_16x16x32_f16(af[fm], bfr[fn], acc[fm][fn], 0, 0, 0);
        }
        __syncthreads();
    }

    long ob = (long)b * sOut;
#pragma unroll
    for (int fm = 0; fm < 2; fm++)
#pragma unroll
        for (int fn = 0; fn < 4; fn++)
#pragma unroll
            for (int r = 0; r < 4; r++) {
                int row = m0 + wm * 32 + fm * 16 + (lane >> 4) * 4 + r;
                int col = n0 + wn * 64 + fn * 16 + (lane & 15);
                Out[ob + (long)row * N + col] = (_Float16)acc[fm][fn][r];
            }
}

// ---------------- fused C + H + score kernel, RES=128, async-STAGE (T14) ----------------
// side C (P < 256):  res = drug l (128 rows), stream = tb p; nsteps=16
// side P (P >= 256): res = tb p (128 rows), stream = drug l; nsteps=8
// 768 blocks = exactly 3/CU (LDS 49.4 KB). XCD swizzle (T1).
// Async-STAGE: step s+1's S/W tiles load into NAMED int4 regs during step s compute
// (named scalars, no arrays/lambda -> no PromoteAlloca-to-LDS, cf. round-10 failure).
__global__ __launch_bounds__(256, 3)
void k_score_fused(const _Float16* __restrict__ drug_h, const _Float16* __restrict__ tb_h,
                   const _Float16* __restrict__ Wxd_h, const _Float16* __restrict__ Wpt_h,
                   const float* __restrict__ whx, const float* __restrict__ whp,
                   float* __restrict__ sc_c, float* __restrict__ sc_p)
{
    __shared__ alignas(16) _Float16 Ss[64 * 136];   // streamed [64][128+8]
    __shared__ alignas(16) _Float16 Ws[64 * 72];    // W slice  [64k][64+8]
    __shared__ alignas(16) _Float16 Cts[128 * 72];  // C tile   [128res][64strm+8]
    __shared__ float sred[8 * 128];
    __shared__ float wsh[64];

    int P = blockIdx.x;
    int tid = threadIdx.x;
    int lane = tid & 63;
    int wid = tid >> 6;
    int wm = wid & 1, wn = wid >> 1;

    int b, n0, nsteps, Ntot, sW;
    const _Float16 *R, *S, *W, *Add;
    const float* wv;
    float* out;
    if (P < 256) {
        int x = P & 7, j = P >> 3;            // j in [0,32)
        b = x * 8 + (j >> 2);                  // batches [8x,8x+8) on XCD x
        n0 = (j & 3) * 128;
        R = drug_h + (long)b * (LD * DD);
        S = tb_h   + (long)b * (LP * DD);
        W = Wpt_h  + (long)b * (KK * LP);  sW = LP;
        Add = Wxd_h + (long)b * (KK * LD); Ntot = LD;
        nsteps = LP / 64; wv = whx; out = sc_c + (long)b * LD;
    } else {
        int Q = P - 256;
        int x = Q & 7, j = Q >> 3;            // j in [0,64)
        b = x * 8 + (j >> 3);
        n0 = (j & 7) * 128;
        R = tb_h   + (long)b * (LP * DD);
        S = drug_h + (long)b * (LD * DD);
        W = Wxd_h  + (long)b * (KK * LD);  sW = LD;
        Add = Wpt_h + (long)b * (KK * LP); Ntot = LP;
        nsteps = LD / 64; wv = whp; out = sc_p + (long)b * LP;
    }

    // resident fragments in registers (MFMA B-operand): 128 rows = wm*64 + fm*16 + (lane&15)
    half8 af[4][4];
#pragma unroll
    for (int fm = 0; fm < 4; fm++)
#pragma unroll
        for (int kk = 0; kk < 4; kk++) {
            int row = n0 + wm * 64 + fm * 16 + (lane & 15);
            int col = kk * 32 + 8 * (lane >> 4);
            af[fm][kk] = *reinterpret_cast<const half8*>(R + (long)row * DD + col);
        }
    if (tid < 64) wsh[tid] = wv[tid];

    // async-STAGE register pipeline (named scalars; affine addresses)
    int rS = tid >> 4, cS = (tid & 15) * 8;     // S rows rS, rS+16, rS+32, rS+48
    int rW = tid >> 3, cW = (tid & 7) * 8;      // W rows rW, rW+32
    int4 s0_, s1_, s2_, s3_, w0_, w1_;
    {
        s0_ = *reinterpret_cast<const int4*>(S + (long)(rS)      * DD + cS);
        s1_ = *reinterpret_cast<const int4*>(S + (long)(rS + 16) * DD + cS);
        s2_ = *reinterpret_cast<const int4*>(S + (long)(rS + 32) * DD + cS);
        s3_ = *reinterpret_cast<const int4*>(S + (long)(rS + 48) * DD + cS);
        w0_ = *reinterpret_cast<const int4*>(W + (long)(rW)      * sW + cW);
        w1_ = *reinterpret_cast<const int4*>(W + (long)(rW + 32) * sW + cW);
    }

    f32x4 acc2[2][4];
#pragma unroll
    for (int i = 0; i < 2; i++)
#pragma unroll
        for (int j = 0; j < 4; j++) acc2[i][j] = (f32x4)(0.0f);

    for (int s = 0; s < nsteps; s++) {
        __syncthreads();                  // (C) prev GEMM2 done; Ss/Ws/Cts free
        // write prefetched regs -> LDS
        *reinterpret_cast<int4*>(&Ss[(rS)      * 136 + cS]) = s0_;
        *reinterpret_cast<int4*>(&Ss[(rS + 16) * 136 + cS]) = s1_;
        *reinterpret_cast<int4*>(&Ss[(rS + 32) * 136 + cS]) = s2_;
        *reinterpret_cast<int4*>(&Ss[(rS + 48) * 136 + cS]) = s3_;
        *reinterpret_cast<int4*>(&Ws[(rW)      * 72 + cW]) = w0_;
        *reinterpret_cast<int4*>(&Ws[(rW + 32) * 72 + cW]) = w1_;
        __syncthreads();                  // (A) staging visible (covers wsh at s=0)
        if (s + 1 < nsteps) {             // prefetch next step; hides under compute below
            int s1n = (s + 1) * 64;
            s0_ = *reinterpret_cast<const int4*>(S + (long)(s1n + rS)      * DD + cS);
            s1_ = *reinterpret_cast<const int4*>(S + (long)(s1n + rS + 16) * DD + cS);
            s2_ = *reinterpret_cast<const int4*>(S + (long)(s1n + rS + 32) * DD + cS);
            s3_ = *reinterpret_cast<const int4*>(S + (long)(s1n + rS + 48) * DD + cS);
            w0_ = *reinterpret_cast<const int4*>(W + (long)(rW)      * sW + s1n + cW);
            w1_ = *reinterpret_cast<const int4*>(W + (long)(rW + 32) * sW + s1n + cW);
        }

        // GEMM1 (swapped): a1[fn][fm] = mfma(S_frag, R_frag)
        //   D: res = wm*64+fm*16+(lane&15), strm = wn*32+fn*16+4*(lane>>4)+r
        f32x4 a1[2][4];
#pragma unroll
        for (int i = 0; i < 2; i++)
#pragma unroll
            for (int j = 0; j < 4; j++) a1[i][j] = (f32x4)(0.0f);
#pragma unroll
        for (int kk = 0; kk < 4; kk++) {
            int klane = kk * 32 + 8 * (lane >> 4);
            half8 bf[2];
#pragma unroll
            for (int fn = 0; fn < 2; fn++)
                bf[fn] = *reinterpret_cast<const half8*>(&Ss[(wn * 32 + fn * 16 + (lane & 15)) * 136 + klane]);
#pragma unroll
            for (int fn = 0; fn < 2; fn++)
#pragma unroll
                for (int fm = 0; fm < 4; fm++)
                    a1[fn][fm] = __builtin_amdgcn_mfma_f32_16x16x32_f16(bf[fn], af[fm][kk], a1[fn][fm], 0, 0, 0);
        }
        // tanh -> Cts [res][strm]: 4 contiguous strm per (fn,fm) -> half4 store
#pragma unroll
        for (int fn = 0; fn < 2; fn++)
#pragma unroll
            for (int fm = 0; fm < 4; fm++) {
                int res   = wm * 64 + fm * 16 + (lane & 15);
                int strm0 = wn * 32 + fn * 16 + 4 * (lane >> 4);
                half4 hv;
                hv.x = (_Float16)ftanh(a1[fn][fm][0]);
                hv.y = (_Float16)ftanh(a1[fn][fm][1]);
                hv.z = (_Float16)ftanh(a1[fn][fm][2]);
                hv.w = (_Float16)ftanh(a1[fn][fm][3]);
                *reinterpret_cast<half4*>(&Cts[res * 72 + strm0]) = hv;
            }
        __syncthreads();                  // (B) Cts ready

        // GEMM2: acc2[k, res] += sum_strm Ws[k,strm]*Cts[res,strm]
#pragma unroll
        for (int kk = 0; kk < 2; kk++) {
            int klane = kk * 32 + 8 * (lane >> 4);
            half8 aw[2], bf2[4];
#pragma unroll
            for (int fm2 = 0; fm2 < 2; fm2++)
                aw[fm2] = *reinterpret_cast<const half8*>(&Ws[(wm * 32 + fm2 * 16 + (lane & 15)) * 72 + klane]);
#pragma unroll
            for (int fn2 = 0; fn2 < 4; fn2++)
                bf2[fn2] = *reinterpret_cast<const half8*>(&Cts[(wn * 64 + fn2 * 16 + (lane & 15)) * 72 + klane]);
#pragma unroll
            for (int fm2 = 0; fm2 < 2; fm2++)
#pragma unroll
                for (int fn2 = 0; fn2 < 4; fn2++)
                    acc2[fm2][fn2] = __builtin_amdgcn_mfma_f32_16x16x32_f16(aw[fm2], bf2[fn2], acc2[fm2][fn2], 0, 0, 0);
        }
    }

    // epilogue: + Add, tanh, dot w, block reduce over k
    float ps[4] = {0.f, 0.f, 0.f, 0.f};
#pragma unroll
    for (int fm2 = 0; fm2 < 2; fm2++)
#pragma unroll
        for (int fn2 = 0; fn2 < 4; fn2++)
#pragma unroll
            for (int r = 0; r < 4; r++) {
                int k   = wm * 32 + fm2 * 16 + (lane >> 4) * 4 + r;
                int col = wn * 64 + fn2 * 16 + (lane & 15);
                float v = ftanh(acc2[fm2][fn2][r] + (float)Add[(long)k * Ntot + n0 + col]);
                ps[fn2] += wsh[k] * v;
            }
#pragma unroll
    for (int fn2 = 0; fn2 < 4; fn2++)
        sred[(wm * 4 + (lane >> 4)) * 128 + wn * 64 + fn2 * 16 + (lane & 15)] = ps[fn2];
    __syncthreads();
    if (tid < 128) {
        float sacc = 0.f;
#pragma unroll
        for (int j = 0; j < 8; j++) sacc += sred[j * 128 + tid];
        out[n0 + tid] = sacc;
    }
}

// ---------------- softmax over scores ----------------
__device__ __forceinline__ float wred_max(float v) {
#pragma unroll
    for (int off = 32; off > 0; off >>= 1) v = fmaxf(v, __shfl_xor(v, off, 64));
    return v;
}
__device__ __forceinline__ float wred_sum(float v) {
#pragma unroll
    for (int off = 32; off > 0; off >>= 1) v += __shfl_xor(v, off, 64);
    return v;
}

__global__ __launch_bounds__(1024)
void k_soft(const float* __restrict__ scc, const float* __restrict__ scp,
            float* __restrict__ ac, float* __restrict__ ap)
{
    __shared__ float r16[16];
    int b = blockIdx.x, tid = threadIdx.x;
    int lane = tid & 63, wid = tid >> 6;

    float s = (tid < 512) ? scc[b * 512 + tid] : -3.4e38f;
    float m = wred_max(s);
    if (lane == 0) r16[wid] = m;
    __syncthreads();
    m = r16[0];
#pragma unroll
    for (int i = 1; i < 16; i++) m = fmaxf(m, r16[i]);
    float e = (tid < 512) ? __expf(s - m) : 0.f;
    __syncthreads();
    float t = wred_sum(e);
    if (lane == 0) r16[wid] = t;
    __syncthreads();
    float sum = 0.f;
#pragma unroll
    for (int i = 0; i < 16; i++) sum += r16[i];
    if (tid < 512) ac[b * 512 + tid] = e * __builtin_amdgcn_rcpf(sum);
    __syncthreads();

    float s2 = scp[b * 1024 + tid];
    float m2 = wred_max(s2);
    if (lane == 0) r16[wid] = m2;
    __syncthreads();
    m2 = r16[0];
#pragma unroll
    for (int i = 1; i < 16; i++) m2 = fmaxf(m2, r16[i]);
    float e2 = __expf(s2 - m2);
    __syncthreads();
    float t2 = wred_sum(e2);
    if (lane == 0) r16[wid] = t2;
    __syncthreads();
    float sum2 = 0.f;
#pragma unroll
    for (int i = 0; i < 16; i++) sum2 += r16[i];
    ap[b * 1024 + tid] = e2 * __builtin_amdgcn_rcpf(sum2);
}

// ---------------- weighted sums: out[b,d] = sum_l a[l] * X[b,l,d] ----------------
__global__ __launch_bounds__(512)
void k_wsum(const _Float16* __restrict__ drug_h, const _Float16* __restrict__ targ_h,
            const float* __restrict__ ac, const float* __restrict__ ap,
            float* __restrict__ out)
{
    __shared__ float ash[1024];
    __shared__ float red[32 * 128];
    int b = blockIdx.x, side = blockIdx.y;
    int L = side ? LP : LD;
    const _Float16* X = side ? targ_h : drug_h;
    const float* a = side ? ap : ac;
    float* ob = out + side * 8192 + b * 128;
    int tid = threadIdx.x;

    for (int i = tid; i < L; i += 512) ash[i] = a[(long)b * L + i];
    __syncthreads();

    int col8 = tid & 15, rg = tid >> 4;
    float accv[8];
#pragma unroll
    for (int j = 0; j < 8; j++) accv[j] = 0.f;
    const _Float16* Xb = X + (long)b * L * 128;
    for (int l = rg; l < L; l += 32) {
        half8 v = *reinterpret_cast<const half8*>(&Xb[l * 128 + col8 * 8]);
        float av = ash[l];
#pragma unroll
        for (int j = 0; j < 8; j++) accv[j] += av * (float)v[j];
    }
#pragma unroll
    for (int j = 0; j < 8; j++) red[rg * 128 + col8 * 8 + j] = accv[j];
    __syncthreads();
    if (tid < 128) {
        float s = 0.f;
#pragma unroll
        for (int g = 0; g < 32; g++) s += red[g * 128 + tid];
        ob[tid] = s;
    }
}

// ---------------- launch ----------------
extern "C" void kernel_launch(void* const* d_in, const int* in_sizes, int n_in,
                              void* d_out, int out_size, void* d_ws, size_t ws_size,
                              hipStream_t stream) {
    (void)in_sizes; (void)n_in; (void)out_size;
    const float* drug   = (const float*)d_in[0];
    const float* target = (const float*)d_in[1];
    const float* Wb     = (const float*)d_in[2];
    const float* Wx     = (const float*)d_in[3];
    const float* Wp     = (const float*)d_in[4];
    const float* whx    = (const float*)d_in[5];
    const float* whp    = (const float*)d_in[6];

    char* w = (char*)d_ws;
    size_t off = 0;
    auto takeb = [&](size_t bytes) {
        void* p = (void*)(w + off);
        off += (bytes + 255) & ~(size_t)255;
        return p;
    };
    _Float16* drug_h = (_Float16*)takeb((size_t)NB * LD * DD * 2);
    _Float16* targ_h = (_Float16*)takeb((size_t)NB * LP * DD * 2);
    _Float16* WbT_h  = (_Float16*)takeb(128 * 128 * 2);
    _Float16* Wx_h   = (_Float16*)takeb(64 * 128 * 2);
    _Float16* Wp_h   = (_Float16*)takeb(64 * 128 * 2);
    _Float16* tb_h   = (_Float16*)takeb((size_t)NB * LP * DD * 2);
    _Float16* Wxd_h  = (_Float16*)takeb((size_t)NB * KK * LD * 2);
    _Float16* Wpt_h  = (_Float16*)takeb((size_t)NB * KK * LP * 2);
    float*    sc_c   = (float*)takeb((size_t)NB * LD * 4);
    float*    sc_p   = (float*)takeb((size_t)NB * LP * 4);
    float*    a_c    = (float*)takeb((size_t)NB * LD * 4);
    float*    a_p    = (float*)takeb((size_t)NB * LP * 4);

    if (off > ws_size) {                 // workspace shortfall -> sentinel (absmax ~1000)
        k_sentinel<<<1, 64, 0, stream>>>((float*)d_out);
        return;
    }

    k_convprep<<<2128, 256, 0, stream>>>(drug, drug_h, target, targ_h,
                                         Wb, WbT_h, Wx, Wx_h, Wp, Wp_h);

    // merged: Wxd + Wpt + tb in one dispatch
    k_gemm3<<<dim3(1792), 256, 0, stream>>>(
        drug_h, targ_h, WbT_h, Wx_h, Wp_h, tb_h, Wxd_h, Wpt_h);

    // fused: C recomputed per side in-LDS; scores out directly (RES=128, 768 blocks)
    k_score_fused<<<dim3(256 + 512), 256, 0, stream>>>(
        drug_h, tb_h, Wxd_h, Wpt_h, whx, whp, sc_c, sc_p);

    k_soft<<<NB, 1024, 0, stream>>>(sc_c, sc_p, a_c, a_p);
    k_wsum<<<dim3(NB, 2), 512, 0, stream>>>(drug_h, targ_h, a_c, a_p, (float*)d_out);
}